// Round 1
// baseline (177.101 us; speedup 1.0000x reference)
//
#include <hip/hip_runtime.h>

// PCLLoss: C=256 classes, N=64 samples/class, D=1024.
// loss = mean_i [ sum_c ( log(eps + S_{i,c}) - pred[i,c] ) ]
// pred = Mv Mv^T, true = Mt Mt^T, Mv/Mt = per-class means of L2-normalized
// rows; S_{i,c} = sum_j exp(pred[i,j]) over j ranked at-or-after c in a
// stable descending sort of true[i,:]  (computed sort-free via an O(C) scan).
//
// R8: k1 = R6 structure + NONTEMPORAL loads (single variable). Six k1
// variants (reg loads at 18-63% occ, LDS staging, prefetch, async DMA)
// all pinned at 46-51 us regardless of issue mechanism / occupancy /
// FETCH mix -> in-flight-bytes model dead. Remaining suspect: L2
// allocation churn on a zero-reuse 134 MB stream (evicts + writes back
// the restore's dirty lines). nt loads skip L2 allocate; write-only
// fills (streaming) hit 6.6 TB/s while allocating reads pin at ~2.8.
//
// R9 (this session, round 0): prior bench attempt died to a container
// infra error; resubmitting identical source to re-baseline + capture
// counters before theorizing further.

#define CC 256
#define NN 64
#define DD 1024
#define PARTS 4
#define TK 128   // K-slice for gram split-K

typedef float v4f __attribute__((ext_vector_type(4)));
__device__ __forceinline__ float4 ntload4(const float* p) {
    v4f v = __builtin_nontemporal_load((const v4f*)p);
    return make_float4(v.x, v.y, v.z, v.w);
}

// ---------------- K1: normalize + partial class sums ------------------
// grid = 2*CC*PARTS = 2048 blocks x 256 thr. Block (t,c,p): 16 rows in 4
// rounds of 4; wave w streams row rnd*4+w into LDS while computing its
// sum-of-squares; all threads then scale-accumulate from LDS at own cols.
__global__ __launch_bounds__(256) void k1_partial(
    const float* __restrict__ emb, const float* __restrict__ feat,
    float* __restrict__ parts /* [2][CC][PARTS][DD] */, float* __restrict__ out)
{
    if (blockIdx.x == 0 && threadIdx.x == 0) out[0] = 0.f;  // for k3b atomics

    int b = blockIdx.x;
    int t = b >> 10;              // tensor
    int c = (b >> 2) & 255;       // class
    int p = b & 3;                // part (16 rows)
    const float* src = (t == 0 ? emb : feat) + ((size_t)c * NN + p * 16) * DD;
    int wave = threadIdx.x >> 6, lane = threadIdx.x & 63;
    int col = threadIdx.x * 4;    // this thread's 4 output columns

    __shared__ float sv[2][4][DD];   // 32 KB row double-buffer
    __shared__ float sinv[2][4];

    float4 v[4], vn[4];
    {
        const float* r0 = src + (size_t)wave * DD;
        #pragma unroll
        for (int k = 0; k < 4; ++k)
            v[k] = ntload4(r0 + k * 256 + lane * 4);
    }

    float4 acc = make_float4(0.f, 0.f, 0.f, 0.f);

    #pragma unroll
    for (int rnd = 0; rnd < 4; ++rnd) {
        int buf = rnd & 1;
        // stage this round's row to LDS; regs also feed local ss, then die
        #pragma unroll
        for (int k = 0; k < 4; ++k)
            *(float4*)&sv[buf][wave][k * 256 + lane * 4] = v[k];
        float ss = 0.f;
        #pragma unroll
        for (int k = 0; k < 4; ++k)
            ss += v[k].x * v[k].x + v[k].y * v[k].y +
                  v[k].z * v[k].z + v[k].w * v[k].w;

        // prefetch next round's row BEFORE the butterfly (nt: no L2 alloc)
        if (rnd < 3) {
            const float* rn = src + (size_t)((rnd + 1) * 4 + wave) * DD;
            #pragma unroll
            for (int k = 0; k < 4; ++k)
                vn[k] = ntload4(rn + k * 256 + lane * 4);
        }

        #pragma unroll
        for (int m = 32; m >= 1; m >>= 1)
            ss += __shfl_xor(ss, m, 64);
        if (lane == 0)
            sinv[buf][wave] = 1.0f / fmaxf(sqrtf(ss), 1e-12f);  // F.normalize eps
        __syncthreads();

        // consume from LDS: 4 b128 reads + broadcast scalars
        float i0 = sinv[buf][0], i1 = sinv[buf][1];
        float i2 = sinv[buf][2], i3 = sinv[buf][3];
        float4 u0 = *(float4*)&sv[buf][0][col];
        float4 u1 = *(float4*)&sv[buf][1][col];
        float4 u2 = *(float4*)&sv[buf][2][col];
        float4 u3 = *(float4*)&sv[buf][3][col];
        acc.x += u0.x * i0 + u1.x * i1 + u2.x * i2 + u3.x * i3;
        acc.y += u0.y * i0 + u1.y * i1 + u2.y * i2 + u3.y * i3;
        acc.z += u0.z * i0 + u1.z * i1 + u2.z * i2 + u3.z * i3;
        acc.w += u0.w * i0 + u1.w * i1 + u2.w * i2 + u3.w * i3;

        if (rnd < 3) {
            #pragma unroll
            for (int k = 0; k < 4; ++k) v[k] = vn[k];
        }
    }

    *(float4*)(parts + (((size_t)t * CC + c) * PARTS + p) * DD + col) = acc;
}

// ---------------- K3a: split-K tiled Gram partials (k2 fused) ---------
// grid = 2 tensors * 16 tiles(64x64) * 8 K-splits = 256 blocks, 256 thr.
// Stages directly from parts: mean = (sum of 4 parts) / N at load time.
__global__ __launch_bounds__(256) void k3a_gram(
    const float* __restrict__ parts, float* __restrict__ gpart /* [2][8][CC][CC] */)
{
    __shared__ float As[64][132];
    __shared__ float Bs[TK][68];

    int b = blockIdx.x;
    int t = b >> 7;
    int r = b & 127;
    int ks = r >> 4;
    int ti = (r >> 2) & 3, tj = r & 3;
    int i0 = ti * 64, j0 = tj * 64, k0 = ks * TK;
    const float invN = 1.0f / (float)NN;

    for (int f = threadIdx.x; f < 64 * 32; f += 256) {
        int row = f >> 5, c4 = f & 31;
        const float* P = parts + ((size_t)(t * CC + i0 + row) * PARTS) * DD + k0 + c4 * 4;
        float4 v0 = *(const float4*)(P);
        float4 v1 = *(const float4*)(P + DD);
        float4 v2 = *(const float4*)(P + 2 * DD);
        float4 v3 = *(const float4*)(P + 3 * DD);
        float4 v = make_float4((v0.x + v1.x + v2.x + v3.x) * invN,
                               (v0.y + v1.y + v2.y + v3.y) * invN,
                               (v0.z + v1.z + v2.z + v3.z) * invN,
                               (v0.w + v1.w + v2.w + v3.w) * invN);
        *(float4*)&As[row][c4 * 4] = v;
    }
    for (int f = threadIdx.x; f < 64 * 32; f += 256) {
        int row = f >> 5, c4 = f & 31;
        const float* P = parts + ((size_t)(t * CC + j0 + row) * PARTS) * DD + k0 + c4 * 4;
        float4 v0 = *(const float4*)(P);
        float4 v1 = *(const float4*)(P + DD);
        float4 v2 = *(const float4*)(P + 2 * DD);
        float4 v3 = *(const float4*)(P + 3 * DD);
        Bs[c4 * 4 + 0][row] = (v0.x + v1.x + v2.x + v3.x) * invN;
        Bs[c4 * 4 + 1][row] = (v0.y + v1.y + v2.y + v3.y) * invN;
        Bs[c4 * 4 + 2][row] = (v0.z + v1.z + v2.z + v3.z) * invN;
        Bs[c4 * 4 + 3][row] = (v0.w + v1.w + v2.w + v3.w) * invN;
    }
    __syncthreads();

    int tr = threadIdx.x >> 4, tc = threadIdx.x & 15;
    float acc[4][4] = {};
    #pragma unroll 4
    for (int kk = 0; kk < TK; kk += 4) {
        float4 a[4], bb[4];
        #pragma unroll
        for (int q = 0; q < 4; ++q) a[q] = *(float4*)&As[tr * 4 + q][kk];
        #pragma unroll
        for (int kq = 0; kq < 4; ++kq) bb[kq] = *(float4*)&Bs[kk + kq][tc * 4];
        #pragma unroll
        for (int q = 0; q < 4; ++q) {
            acc[q][0] += a[q].x * bb[0].x + a[q].y * bb[1].x + a[q].z * bb[2].x + a[q].w * bb[3].x;
            acc[q][1] += a[q].x * bb[0].y + a[q].y * bb[1].y + a[q].z * bb[2].y + a[q].w * bb[3].y;
            acc[q][2] += a[q].x * bb[0].z + a[q].y * bb[1].z + a[q].z * bb[2].z + a[q].w * bb[3].z;
            acc[q][3] += a[q].x * bb[0].w + a[q].y * bb[1].w + a[q].z * bb[2].w + a[q].w * bb[3].w;
        }
    }

    float* G = gpart + (((size_t)(t * 8 + ks) * CC) + i0 + tr * 4) * CC + j0 + tc * 4;
    #pragma unroll
    for (int q = 0; q < 4; ++q)
        *(float4*)(G + (size_t)q * CC) =
            make_float4(acc[q][0], acc[q][1], acc[q][2], acc[q][3]);
}

// ---------------- K3b: reduce partials + ListMLE + final mean ---------
// grid = CC blocks; one atomicAdd per block into out (zeroed by k1).
__global__ __launch_bounds__(256) void k3b_listmle(
    const float* __restrict__ gpart, float* __restrict__ out)
{
    int i = blockIdx.x, c = threadIdx.x;
    float dp = 0.f, dt = 0.f;
    #pragma unroll
    for (int ks = 0; ks < 8; ++ks) {
        dp += gpart[((size_t)ks * CC + i) * CC + c];
        dt += gpart[((size_t)(8 + ks) * CC + i) * CC + c];
    }

    __shared__ float s_true[CC];
    __shared__ float s_pexp[CC];
    s_true[c] = dt;
    s_pexp[c] = expf(dp);
    __syncthreads();

    // S = sum exp(pred_j) over j ranked at-or-after c (stable desc by true)
    float S = 0.f;
    for (int j = 0; j < CC; ++j) {
        float tj = s_true[j];
        bool take = (tj < dt) || (tj == dt && j >= c);
        S += take ? s_pexp[j] : 0.f;
    }
    float contrib = logf(S + 1e-10f) - dp;

    #pragma unroll
    for (int m = 32; m >= 1; m >>= 1)
        contrib += __shfl_xor(contrib, m, 64);
    __shared__ float s_red[4];
    if ((c & 63) == 0) s_red[c >> 6] = contrib;
    __syncthreads();
    if (c == 0)
        atomicAdd(out, (s_red[0] + s_red[1] + s_red[2] + s_red[3]) * (1.0f / (float)CC));
}

extern "C" void kernel_launch(void* const* d_in, const int* in_sizes, int n_in,
                              void* d_out, int out_size, void* d_ws, size_t ws_size,
                              hipStream_t stream) {
    const float* emb  = (const float*)d_in[0];
    const float* feat = (const float*)d_in[1];
    float* ws = (float*)d_ws;
    float* parts = ws;                                  // 2*CC*PARTS*DD = 8 MiB
    float* gpart = parts + (size_t)2 * CC * PARTS * DD; // 2*8*CC*CC = 4 MiB

    k1_partial <<<2 * CC * PARTS, 256, 0, stream>>>(emb, feat, parts, (float*)d_out);
    k3a_gram   <<<256, 256, 0, stream>>>(parts, gpart);
    k3b_listmle<<<CC, 256, 0, stream>>>(gpart, (float*)d_out);
}

// Round 2
// 171.969 us; speedup vs baseline: 1.0298x; 1.0298x over previous
//
#include <hip/hip_runtime.h>

// PCLLoss: C=256 classes, N=64 samples/class, D=1024.
// loss = mean_i [ sum_c ( log(eps + S_{i,c}) - pred[i,c] ) ]
// pred = Mv Mv^T, true = Mt Mt^T, Mv/Mt = per-class means of L2-normalized
// rows; S_{i,c} = sum_j exp(pred[i,j]) over j ranked at-or-after c in a
// stable descending sort of true[i,:]  (computed sort-free via an O(C) scan).
//
// R9 findings (counters): the 177 us headline is ~70% harness re-poison —
// three 256 MiB fillBuffer dispatches @40.8 us inside the timed window.
// None of our kernels exceeds 40.7 us. Addressable budget is ~55 us.
//
// R10 (this round): PARTS 4 -> 1. k1 now reduces all 64 rows per class and
// writes finished means (2 MiB instead of 8 MiB of partials); k3a stages
// means directly (17 MB total staged traffic, L2-resident) instead of
// re-reading 67 MB of partials with a 4-way sum at load. k3a split-K 8->16
// with TK 128->64: LDS 68.6->34.8 KB, grid 256->512 = 2 blocks/CU instead
// of 1 (was 1 wave/SIMD, occupancy-starved). k1 stream structure unchanged
// (nt loads, 4-row double-buffered rounds) per R8's occupancy-insensitivity.

#define CC 256
#define NN 64
#define DD 1024
#define KS 16   // K-splits for gram
#define TK 64   // K-slice per gram block

typedef float v4f __attribute__((ext_vector_type(4)));
__device__ __forceinline__ float4 ntload4(const float* p) {
    v4f v = __builtin_nontemporal_load((const v4f*)p);
    return make_float4(v.x, v.y, v.z, v.w);
}

// ---------------- K1: normalize + full class mean ---------------------
// grid = 2*CC = 512 blocks x 256 thr. Block (t,c): 64 rows in 16 rounds
// of 4; wave w streams row rnd*4+w into LDS while computing its
// sum-of-squares; all threads then scale-accumulate from LDS at own cols.
// Writes the finished mean (x 1/N) -- 2 MiB total.
__global__ __launch_bounds__(256) void k1_mean(
    const float* __restrict__ emb, const float* __restrict__ feat,
    float* __restrict__ means /* [2][CC][DD] */, float* __restrict__ out)
{
    if (blockIdx.x == 0 && threadIdx.x == 0) out[0] = 0.f;  // for k3b atomics

    int b = blockIdx.x;
    int t = b >> 8;               // tensor
    int c = b & 255;              // class
    const float* src = (t == 0 ? emb : feat) + (size_t)c * NN * DD;
    int wave = threadIdx.x >> 6, lane = threadIdx.x & 63;
    int col = threadIdx.x * 4;    // this thread's 4 output columns

    __shared__ float sv[2][4][DD];   // 32 KB row double-buffer
    __shared__ float sinv[2][4];

    float4 v[4], vn[4];
    {
        const float* r0 = src + (size_t)wave * DD;
        #pragma unroll
        for (int k = 0; k < 4; ++k)
            v[k] = ntload4(r0 + k * 256 + lane * 4);
    }

    float4 acc = make_float4(0.f, 0.f, 0.f, 0.f);

    for (int rnd = 0; rnd < 16; ++rnd) {
        int buf = rnd & 1;
        // stage this round's row to LDS; regs also feed local ss, then die
        #pragma unroll
        for (int k = 0; k < 4; ++k)
            *(float4*)&sv[buf][wave][k * 256 + lane * 4] = v[k];
        float ss = 0.f;
        #pragma unroll
        for (int k = 0; k < 4; ++k)
            ss += v[k].x * v[k].x + v[k].y * v[k].y +
                  v[k].z * v[k].z + v[k].w * v[k].w;

        // prefetch next round's row BEFORE the butterfly (nt: no L2 alloc)
        if (rnd < 15) {
            const float* rn = src + (size_t)((rnd + 1) * 4 + wave) * DD;
            #pragma unroll
            for (int k = 0; k < 4; ++k)
                vn[k] = ntload4(rn + k * 256 + lane * 4);
        }

        #pragma unroll
        for (int m = 32; m >= 1; m >>= 1)
            ss += __shfl_xor(ss, m, 64);
        if (lane == 0)
            sinv[buf][wave] = 1.0f / fmaxf(sqrtf(ss), 1e-12f);  // F.normalize eps
        __syncthreads();

        // consume from LDS: 4 b128 reads + broadcast scalars
        float i0 = sinv[buf][0], i1 = sinv[buf][1];
        float i2 = sinv[buf][2], i3 = sinv[buf][3];
        float4 u0 = *(float4*)&sv[buf][0][col];
        float4 u1 = *(float4*)&sv[buf][1][col];
        float4 u2 = *(float4*)&sv[buf][2][col];
        float4 u3 = *(float4*)&sv[buf][3][col];
        acc.x += u0.x * i0 + u1.x * i1 + u2.x * i2 + u3.x * i3;
        acc.y += u0.y * i0 + u1.y * i1 + u2.y * i2 + u3.y * i3;
        acc.z += u0.z * i0 + u1.z * i1 + u2.z * i2 + u3.z * i3;
        acc.w += u0.w * i0 + u1.w * i1 + u2.w * i2 + u3.w * i3;

        if (rnd < 15) {
            #pragma unroll
            for (int k = 0; k < 4; ++k) v[k] = vn[k];
        }
    }

    const float invN = 1.0f / (float)NN;
    *(float4*)(means + ((size_t)t * CC + c) * DD + col) =
        make_float4(acc.x * invN, acc.y * invN, acc.z * invN, acc.w * invN);
}

// ---------------- K3a: split-K tiled Gram partials --------------------
// grid = 2 tensors * 16 tiles(64x64) * KS K-splits = 512 blocks, 256 thr.
// LDS 34.8 KB -> 2 blocks/CU resident (was 1). Stages finished means.
__global__ __launch_bounds__(256) void k3a_gram(
    const float* __restrict__ means, float* __restrict__ gpart /* [2][KS][CC][CC] */)
{
    __shared__ float As[64][TK + 4];
    __shared__ float Bs[TK][68];

    int b = blockIdx.x;
    int t = b >> 8;
    int r = b & 255;
    int ks = r >> 4;
    int ti = (r >> 2) & 3, tj = r & 3;
    int i0 = ti * 64, j0 = tj * 64, k0 = ks * TK;

    for (int f = threadIdx.x; f < 64 * (TK / 4); f += 256) {
        int row = f >> 4, c4 = f & 15;
        float4 v = *(const float4*)(means + ((size_t)(t * CC + i0 + row)) * DD + k0 + c4 * 4);
        *(float4*)&As[row][c4 * 4] = v;
    }
    for (int f = threadIdx.x; f < 64 * (TK / 4); f += 256) {
        int row = f >> 4, c4 = f & 15;
        float4 v = *(const float4*)(means + ((size_t)(t * CC + j0 + row)) * DD + k0 + c4 * 4);
        Bs[c4 * 4 + 0][row] = v.x;
        Bs[c4 * 4 + 1][row] = v.y;
        Bs[c4 * 4 + 2][row] = v.z;
        Bs[c4 * 4 + 3][row] = v.w;
    }
    __syncthreads();

    int tr = threadIdx.x >> 4, tc = threadIdx.x & 15;
    float acc[4][4] = {};
    #pragma unroll 4
    for (int kk = 0; kk < TK; kk += 4) {
        float4 a[4], bb[4];
        #pragma unroll
        for (int q = 0; q < 4; ++q) a[q] = *(float4*)&As[tr * 4 + q][kk];
        #pragma unroll
        for (int kq = 0; kq < 4; ++kq) bb[kq] = *(float4*)&Bs[kk + kq][tc * 4];
        #pragma unroll
        for (int q = 0; q < 4; ++q) {
            acc[q][0] += a[q].x * bb[0].x + a[q].y * bb[1].x + a[q].z * bb[2].x + a[q].w * bb[3].x;
            acc[q][1] += a[q].x * bb[0].y + a[q].y * bb[1].y + a[q].z * bb[2].y + a[q].w * bb[3].y;
            acc[q][2] += a[q].x * bb[0].z + a[q].y * bb[1].z + a[q].z * bb[2].z + a[q].w * bb[3].z;
            acc[q][3] += a[q].x * bb[0].w + a[q].y * bb[1].w + a[q].z * bb[2].w + a[q].w * bb[3].w;
        }
    }

    float* G = gpart + (((size_t)(t * KS + ks) * CC) + i0 + tr * 4) * CC + j0 + tc * 4;
    #pragma unroll
    for (int q = 0; q < 4; ++q)
        *(float4*)(G + (size_t)q * CC) =
            make_float4(acc[q][0], acc[q][1], acc[q][2], acc[q][3]);
}

// ---------------- K3b: reduce partials + ListMLE + final mean ---------
// grid = CC blocks; one atomicAdd per block into out (zeroed by k1).
__global__ __launch_bounds__(256) void k3b_listmle(
    const float* __restrict__ gpart, float* __restrict__ out)
{
    int i = blockIdx.x, c = threadIdx.x;
    float dp = 0.f, dt = 0.f;
    #pragma unroll
    for (int ks = 0; ks < KS; ++ks) {
        dp += gpart[((size_t)ks * CC + i) * CC + c];
        dt += gpart[((size_t)(KS + ks) * CC + i) * CC + c];
    }

    __shared__ float s_true[CC];
    __shared__ float s_pexp[CC];
    s_true[c] = dt;
    s_pexp[c] = expf(dp);
    __syncthreads();

    // S = sum exp(pred_j) over j ranked at-or-after c (stable desc by true)
    float S = 0.f;
    for (int j = 0; j < CC; ++j) {
        float tj = s_true[j];
        bool take = (tj < dt) || (tj == dt && j >= c);
        S += take ? s_pexp[j] : 0.f;
    }
    float contrib = logf(S + 1e-10f) - dp;

    #pragma unroll
    for (int m = 32; m >= 1; m >>= 1)
        contrib += __shfl_xor(contrib, m, 64);
    __shared__ float s_red[4];
    if ((c & 63) == 0) s_red[c >> 6] = contrib;
    __syncthreads();
    if (c == 0)
        atomicAdd(out, (s_red[0] + s_red[1] + s_red[2] + s_red[3]) * (1.0f / (float)CC));
}

extern "C" void kernel_launch(void* const* d_in, const int* in_sizes, int n_in,
                              void* d_out, int out_size, void* d_ws, size_t ws_size,
                              hipStream_t stream) {
    const float* emb  = (const float*)d_in[0];
    const float* feat = (const float*)d_in[1];
    float* ws = (float*)d_ws;
    float* means = ws;                               // 2*CC*DD = 2 MiB
    float* gpart = means + (size_t)2 * CC * DD;      // 2*KS*CC*CC = 8 MiB

    k1_mean    <<<2 * CC, 256, 0, stream>>>(emb, feat, means, (float*)d_out);
    k3a_gram   <<<2 * 16 * KS, 256, 0, stream>>>(means, gpart);
    k3b_listmle<<<CC, 256, 0, stream>>>(gpart, (float*)d_out);
}

// Round 4
// 171.548 us; speedup vs baseline: 1.0324x; 1.0025x over previous
//
#include <hip/hip_runtime.h>

// PCLLoss: C=256 classes, N=64 samples/class, D=1024.
// loss = mean_i [ sum_c ( log(eps + S_{i,c}) - pred[i,c] ) ]
// pred = Mv Mv^T, true = Mt Mt^T, Mv/Mt = per-class means of L2-normalized
// rows; S_{i,c} = sum_j exp(pred[i,j]) over j ranked at-or-after c in a
// stable descending sort of true[i,:]  (computed sort-free via an O(C) scan).
//
// R9: 177 us headline is ~70% harness re-poison (3x 256 MiB fills @40.3 us,
// 6.6 TB/s). R10: PARTS 4->1 + k3a TK=64/KS=16: 177.1 -> 172.0 us.
//
// R11: k1's ~40 us @ "3.35 TB/s" decoded. FETCH/WRITE_SIZE are TCC(L2)
// counters, so the fill's 256 MiB lands DIRTY in the 256 MiB MALL. k1's
// 134 MB read then evicts a dirty line per miss -> ~134 MB victim
// writeback; 268 MB at 6.6 TB/s = 40.6 us = observed. Probe: stream loads
// with sc0 sc1 nt (system-scope non-temporal) via inline asm to skip MALL
// allocation; dirty fill lines stay put and get overwritten in-place by the
// next fill. Explicit vmcnt fences + sched_barrier guard the asm loads
// (compiler doesn't track asm load latency - rule #18).
//
// R12 (this round): prior attempt died to container infra (same signature
// as R9's flake, which a clean resubmit cured). Diff re-audited: addresses
// in-bounds, encoding gfx950-valid, no new sync hazards. Resubmitting the
// R11 probe unchanged.

#define CC 256
#define NN 64
#define DD 1024
#define KS 16   // K-splits for gram
#define TK 64   // K-slice per gram block

typedef float v4f __attribute__((ext_vector_type(4)));

// 4x16B streaming loads of one row-quarter: base + {0,1024,2048,3072} bytes.
// sc0 sc1 nt = system-scope non-temporal: forced L2 miss, no-allocate hint
// all the way out (probe: does MALL honor it?).
__device__ __forceinline__ void stream_row_load(v4f v[4], const float* p) {
    asm volatile("global_load_dwordx4 %0, %1, off sc0 sc1 nt"
                 : "=v"(v[0]) : "v"(p));
    asm volatile("global_load_dwordx4 %0, %1, off offset:1024 sc0 sc1 nt"
                 : "=v"(v[1]) : "v"(p));
    asm volatile("global_load_dwordx4 %0, %1, off offset:2048 sc0 sc1 nt"
                 : "=v"(v[2]) : "v"(p));
    asm volatile("global_load_dwordx4 %0, %1, off offset:3072 sc0 sc1 nt"
                 : "=v"(v[3]) : "v"(p));
}
__device__ __forceinline__ void drain_vmem() {
    asm volatile("s_waitcnt vmcnt(0)" ::: "memory");
    __builtin_amdgcn_sched_barrier(0);
}

// ---------------- K1: normalize + full class mean ---------------------
// grid = 2*CC = 512 blocks x 256 thr. Block (t,c): 64 rows in 16 rounds
// of 4; wave w streams row rnd*4+w into LDS while computing its
// sum-of-squares; all threads then scale-accumulate from LDS at own cols.
// Writes the finished mean (x 1/N) -- 2 MiB total.
__global__ __launch_bounds__(256) void k1_mean(
    const float* __restrict__ emb, const float* __restrict__ feat,
    float* __restrict__ means /* [2][CC][DD] */, float* __restrict__ out)
{
    if (blockIdx.x == 0 && threadIdx.x == 0) out[0] = 0.f;  // for k3b atomics

    int b = blockIdx.x;
    int t = b >> 8;               // tensor
    int c = b & 255;              // class
    const float* src = (t == 0 ? emb : feat) + (size_t)c * NN * DD;
    int wave = threadIdx.x >> 6, lane = threadIdx.x & 63;
    int col = threadIdx.x * 4;    // this thread's 4 output columns

    __shared__ float sv[2][4][DD];   // 32 KB row double-buffer
    __shared__ float sinv[2][4];

    v4f v[4], vn[4];
    stream_row_load(v, src + (size_t)wave * DD + lane * 4);
    drain_vmem();   // round 0 stages v immediately; asm loads need explicit wait

    float4 acc = make_float4(0.f, 0.f, 0.f, 0.f);

    for (int rnd = 0; rnd < 16; ++rnd) {
        int buf = rnd & 1;
        // stage this round's row to LDS; regs also feed local ss, then die
        #pragma unroll
        for (int k = 0; k < 4; ++k)
            *(v4f*)&sv[buf][wave][k * 256 + lane * 4] = v[k];
        float ss = 0.f;
        #pragma unroll
        for (int k = 0; k < 4; ++k)
            ss += v[k].x * v[k].x + v[k].y * v[k].y +
                  v[k].z * v[k].z + v[k].w * v[k].w;

        // prefetch next round's row BEFORE the butterfly (streaming, no alloc)
        if (rnd < 15)
            stream_row_load(vn, src + (size_t)((rnd + 1) * 4 + wave) * DD + lane * 4);

        #pragma unroll
        for (int m = 32; m >= 1; m >>= 1)
            ss += __shfl_xor(ss, m, 64);
        if (lane == 0)
            sinv[buf][wave] = 1.0f / fmaxf(sqrtf(ss), 1e-12f);  // F.normalize eps
        __syncthreads();

        // consume from LDS: 4 b128 reads + broadcast scalars
        float i0 = sinv[buf][0], i1 = sinv[buf][1];
        float i2 = sinv[buf][2], i3 = sinv[buf][3];
        float4 u0 = *(float4*)&sv[buf][0][col];
        float4 u1 = *(float4*)&sv[buf][1][col];
        float4 u2 = *(float4*)&sv[buf][2][col];
        float4 u3 = *(float4*)&sv[buf][3][col];
        acc.x += u0.x * i0 + u1.x * i1 + u2.x * i2 + u3.x * i3;
        acc.y += u0.y * i0 + u1.y * i1 + u2.y * i2 + u3.y * i3;
        acc.z += u0.z * i0 + u1.z * i1 + u2.z * i2 + u3.z * i3;
        acc.w += u0.w * i0 + u1.w * i1 + u2.w * i2 + u3.w * i3;

        if (rnd < 15) {
            // vn's loads must be complete before the reg-copies below;
            // explicit drain (compiler doesn't track asm loads - rule #18).
            drain_vmem();
            #pragma unroll
            for (int k = 0; k < 4; ++k) v[k] = vn[k];
        }
    }

    const float invN = 1.0f / (float)NN;
    *(float4*)(means + ((size_t)t * CC + c) * DD + col) =
        make_float4(acc.x * invN, acc.y * invN, acc.z * invN, acc.w * invN);
}

// ---------------- K3a: split-K tiled Gram partials --------------------
// grid = 2 tensors * 16 tiles(64x64) * KS K-splits = 512 blocks, 256 thr.
// LDS 34.8 KB -> 2 blocks/CU resident. Stages finished means (L2-resident,
// allocating loads on purpose).
__global__ __launch_bounds__(256) void k3a_gram(
    const float* __restrict__ means, float* __restrict__ gpart /* [2][KS][CC][CC] */)
{
    __shared__ float As[64][TK + 4];
    __shared__ float Bs[TK][68];

    int b = blockIdx.x;
    int t = b >> 8;
    int r = b & 255;
    int ks = r >> 4;
    int ti = (r >> 2) & 3, tj = r & 3;
    int i0 = ti * 64, j0 = tj * 64, k0 = ks * TK;

    for (int f = threadIdx.x; f < 64 * (TK / 4); f += 256) {
        int row = f >> 4, c4 = f & 15;
        float4 v = *(const float4*)(means + ((size_t)(t * CC + i0 + row)) * DD + k0 + c4 * 4);
        *(float4*)&As[row][c4 * 4] = v;
    }
    for (int f = threadIdx.x; f < 64 * (TK / 4); f += 256) {
        int row = f >> 4, c4 = f & 15;
        float4 v = *(const float4*)(means + ((size_t)(t * CC + j0 + row)) * DD + k0 + c4 * 4);
        Bs[c4 * 4 + 0][row] = v.x;
        Bs[c4 * 4 + 1][row] = v.y;
        Bs[c4 * 4 + 2][row] = v.z;
        Bs[c4 * 4 + 3][row] = v.w;
    }
    __syncthreads();

    int tr = threadIdx.x >> 4, tc = threadIdx.x & 15;
    float acc[4][4] = {};
    #pragma unroll 4
    for (int kk = 0; kk < TK; kk += 4) {
        float4 a[4], bb[4];
        #pragma unroll
        for (int q = 0; q < 4; ++q) a[q] = *(float4*)&As[tr * 4 + q][kk];
        #pragma unroll
        for (int kq = 0; kq < 4; ++kq) bb[kq] = *(float4*)&Bs[kk + kq][tc * 4];
        #pragma unroll
        for (int q = 0; q < 4; ++q) {
            acc[q][0] += a[q].x * bb[0].x + a[q].y * bb[1].x + a[q].z * bb[2].x + a[q].w * bb[3].x;
            acc[q][1] += a[q].x * bb[0].y + a[q].y * bb[1].y + a[q].z * bb[2].y + a[q].w * bb[3].y;
            acc[q][2] += a[q].x * bb[0].z + a[q].y * bb[1].z + a[q].z * bb[2].z + a[q].w * bb[3].z;
            acc[q][3] += a[q].x * bb[0].w + a[q].y * bb[1].w + a[q].z * bb[2].w + a[q].w * bb[3].w;
        }
    }

    float* G = gpart + (((size_t)(t * KS + ks) * CC) + i0 + tr * 4) * CC + j0 + tc * 4;
    #pragma unroll
    for (int q = 0; q < 4; ++q)
        *(float4*)(G + (size_t)q * CC) =
            make_float4(acc[q][0], acc[q][1], acc[q][2], acc[q][3]);
}

// ---------------- K3b: reduce partials + ListMLE + final mean ---------
// grid = CC blocks; one atomicAdd per block into out (zeroed by k1).
__global__ __launch_bounds__(256) void k3b_listmle(
    const float* __restrict__ gpart, float* __restrict__ out)
{
    int i = blockIdx.x, c = threadIdx.x;
    float dp = 0.f, dt = 0.f;
    #pragma unroll
    for (int ks = 0; ks < KS; ++ks) {
        dp += gpart[((size_t)ks * CC + i) * CC + c];
        dt += gpart[((size_t)(KS + ks) * CC + i) * CC + c];
    }

    __shared__ float s_true[CC];
    __shared__ float s_pexp[CC];
    s_true[c] = dt;
    s_pexp[c] = expf(dp);
    __syncthreads();

    // S = sum exp(pred_j) over j ranked at-or-after c (stable desc by true)
    float S = 0.f;
    for (int j = 0; j < CC; ++j) {
        float tj = s_true[j];
        bool take = (tj < dt) || (tj == dt && j >= c);
        S += take ? s_pexp[j] : 0.f;
    }
    float contrib = logf(S + 1e-10f) - dp;

    #pragma unroll
    for (int m = 32; m >= 1; m >>= 1)
        contrib += __shfl_xor(contrib, m, 64);
    __shared__ float s_red[4];
    if ((c & 63) == 0) s_red[c >> 6] = contrib;
    __syncthreads();
    if (c == 0)
        atomicAdd(out, (s_red[0] + s_red[1] + s_red[2] + s_red[3]) * (1.0f / (float)CC));
}

extern "C" void kernel_launch(void* const* d_in, const int* in_sizes, int n_in,
                              void* d_out, int out_size, void* d_ws, size_t ws_size,
                              hipStream_t stream) {
    const float* emb  = (const float*)d_in[0];
    const float* feat = (const float*)d_in[1];
    float* ws = (float*)d_ws;
    float* means = ws;                               // 2*CC*DD = 2 MiB
    float* gpart = means + (size_t)2 * CC * DD;      // 2*KS*CC*CC = 8 MiB

    k1_mean    <<<2 * CC, 256, 0, stream>>>(emb, feat, means, (float*)d_out);
    k3a_gram   <<<2 * 16 * KS, 256, 0, stream>>>(means, gpart);
    k3b_listmle<<<CC, 256, 0, stream>>>(gpart, (float*)d_out);
}